// Round 1
// baseline (31891.473 us; speedup 1.0000x reference)
//
#include <hip/hip_runtime.h>
#include <math.h>

#define N_NODES 16384
#define N_EDGES 524288
#define N_GRAPHS 64
#define HID 128
#define FILT 128
#define NG 51
#define NL 6

__device__ __forceinline__ float ssp(float x) {
    // softplus(x) - log(2)
    float sp = (x > 20.0f) ? x : log1pf(__expf(x));
    return sp - 0.6931471805599453f;
}

// h[n][c] = emb_table[z[n]][c]
__global__ void k_embed(const int* __restrict__ z, const float* __restrict__ emb,
                        float* __restrict__ h) {
    int i = blockIdx.x * blockDim.x + threadIdx.x;   // over N_NODES*HID
    int n = i >> 7, c = i & 127;
    h[i] = emb[z[n] * HID + c];
}

// edge_weight[e] = ||pos[row] - pos[col]||
__global__ void k_ew(const float* __restrict__ pos, const int* __restrict__ ei,
                     float* __restrict__ ew) {
    int e = blockIdx.x * blockDim.x + threadIdx.x;
    if (e >= N_EDGES) return;
    int r = ei[e], c = ei[N_EDGES + e];
    float dx = pos[r * 3 + 0] - pos[c * 3 + 0];
    float dy = pos[r * 3 + 1] - pos[c * 3 + 1];
    float dz = pos[r * 3 + 2] - pos[c * 3 + 2];
    ew[e] = sqrtf(dx * dx + dy * dy + dz * dz);
}

// xh = h @ cl1_w[i]   (no bias). W layout [in=HID][out=FILT].
__global__ __launch_bounds__(1024) void k_xh(const float* __restrict__ h,
                                             const float* __restrict__ W,
                                             float* __restrict__ xh) {
    __shared__ float Ws[HID * FILT];                 // 64 KB
    for (int i = threadIdx.x; i < HID * FILT; i += 1024) Ws[i] = W[i];
    __syncthreads();
    int g = threadIdx.x >> 7, c = threadIdx.x & 127;
    for (int n = blockIdx.x * 8 + g; n < N_NODES; n += gridDim.x * 8) {
        const float* hr = h + n * HID;
        float acc = 0.f;
        #pragma unroll 8
        for (int k = 0; k < HID; ++k) acc += hr[k] * Ws[k * FILT + c];
        xh[n * FILT + c] = acc;
    }
}

// Fused per-edge: gaussian smearing -> MLP1 -> ssp -> MLP2 -> *C -> *xh[col] -> atomicAdd agg[row]
// Block = 1024 threads = 8 groups x 128 channels; each tile = 64 edges (8 per group-thread).
__global__ __launch_bounds__(1024) void k_edge(
    const float* __restrict__ ew, const int* __restrict__ ei,
    const float* __restrict__ xh,
    const float* __restrict__ W1, const float* __restrict__ B1,
    const float* __restrict__ W2, const float* __restrict__ B2,
    float* __restrict__ agg)
{
    __shared__ float W1s[NG * FILT];    // 26112 B
    __shared__ float W2s[FILT * FILT];  // 65536 B
    __shared__ float b1s[FILT], b2s[FILT];
    __shared__ float eas[64 * NG];      // 13056 B
    __shared__ float ts[64 * FILT];     // 32768 B
    __shared__ float Cs[64];
    for (int i = threadIdx.x; i < NG * FILT; i += 1024) W1s[i] = W1[i];
    for (int i = threadIdx.x; i < FILT * FILT; i += 1024) W2s[i] = W2[i];
    if (threadIdx.x < FILT) { b1s[threadIdx.x] = B1[threadIdx.x]; b2s[threadIdx.x] = B2[threadIdx.x]; }
    __syncthreads();
    const int g = threadIdx.x >> 7;
    const int c = threadIdx.x & 127;
    const float PI_OVER_CUT = 0.3141592653589793f;  // pi / 10
    for (int tile = blockIdx.x; tile < N_EDGES / 64; tile += gridDim.x) {
        const int e0 = tile * 64;
        // fill eas (64 x NG) and Cs
        for (int idx = threadIdx.x; idx < 64 * NG; idx += 1024) {
            int el = idx / NG, k = idx - el * NG;
            float d = ew[e0 + el] - 0.2f * (float)k;
            eas[idx] = __expf(-12.5f * d * d);
        }
        if (threadIdx.x < 64) {
            float d = ew[e0 + threadIdx.x];
            Cs[threadIdx.x] = 0.5f * (__cosf(d * PI_OVER_CUT) + 1.0f);
        }
        __syncthreads();
        float acc[8];
        #pragma unroll
        for (int j = 0; j < 8; ++j) acc[j] = b1s[c];
        for (int k = 0; k < NG; ++k) {
            float w = W1s[k * FILT + c];
            #pragma unroll
            for (int j = 0; j < 8; ++j) acc[j] += eas[(g * 8 + j) * NG + k] * w;
        }
        #pragma unroll
        for (int j = 0; j < 8; ++j) ts[(g * 8 + j) * FILT + c] = ssp(acc[j]);
        __syncthreads();
        #pragma unroll
        for (int j = 0; j < 8; ++j) acc[j] = b2s[c];
        for (int k = 0; k < FILT; ++k) {
            float w = W2s[k * FILT + c];
            #pragma unroll
            for (int j = 0; j < 8; ++j) acc[j] += ts[(g * 8 + j) * FILT + k] * w;
        }
        #pragma unroll
        for (int j = 0; j < 8; ++j) {
            int e = e0 + g * 8 + j;
            int r = ei[e], cl = ei[N_EDGES + e];
            float wv = acc[j] * Cs[g * 8 + j];
            atomicAdd(&agg[r * FILT + c], xh[cl * FILT + c] * wv);
        }
        __syncthreads();
    }
}

// Fused node MLP: out = ssp(X@W1 + B1) @ W2 + B2 ; Hout = (RESID ? Hin + out : out)
// Block = 1024 = 8 groups x 128 channels; tile = 32 nodes (4 per group-thread).
template<bool RESID>
__global__ __launch_bounds__(1024) void k_node(
    const float* __restrict__ X,
    const float* __restrict__ W1, const float* __restrict__ B1,
    const float* __restrict__ W2, const float* __restrict__ B2,
    const float* __restrict__ Hin, float* __restrict__ Hout)
{
    __shared__ float W1s[HID * FILT];   // 64 KB
    __shared__ float W2s[FILT * HID];   // 64 KB
    __shared__ float ts[32 * FILT];     // 16 KB
    for (int i = threadIdx.x; i < HID * FILT; i += 1024) { W1s[i] = W1[i]; W2s[i] = W2[i]; }
    __syncthreads();
    const int g = threadIdx.x >> 7;
    const int c = threadIdx.x & 127;
    for (int tile = blockIdx.x; tile < N_NODES / 32; tile += gridDim.x) {
        int n0 = tile * 32 + g * 4;
        float acc[4];
        #pragma unroll
        for (int j = 0; j < 4; ++j) acc[j] = B1[c];
        for (int k = 0; k < HID; ++k) {
            float w = W1s[k * FILT + c];
            #pragma unroll
            for (int j = 0; j < 4; ++j) acc[j] += X[(n0 + j) * HID + k] * w;
        }
        #pragma unroll
        for (int j = 0; j < 4; ++j) ts[(g * 4 + j) * FILT + c] = ssp(acc[j]);
        __syncthreads();
        #pragma unroll
        for (int j = 0; j < 4; ++j) acc[j] = B2[c];
        for (int k = 0; k < FILT; ++k) {
            float w = W2s[k * HID + c];
            #pragma unroll
            for (int j = 0; j < 4; ++j) acc[j] += ts[(g * 4 + j) * FILT + k] * w;
        }
        #pragma unroll
        for (int j = 0; j < 4; ++j) {
            float o = acc[j];
            if (RESID) o += Hin[(n0 + j) * HID + c];
            Hout[(n0 + j) * HID + c] = o;
        }
        __syncthreads();
    }
}

// Mean-pool per graph via binary search on sorted batch. 64 blocks x 128 threads.
__global__ void k_pool(const float* __restrict__ hout, const int* __restrict__ batch,
                       float* __restrict__ out) {
    int g = blockIdx.x;
    int c = threadIdx.x;
    int a = 0, b = N_NODES;
    while (a < b) { int m = (a + b) >> 1; if (batch[m] < g) a = m + 1; else b = m; }
    int lo = a;
    b = N_NODES;
    while (a < b) { int m = (a + b) >> 1; if (batch[m] < g + 1) a = m + 1; else b = m; }
    int hi = a;
    float s = 0.f;
    for (int n = lo; n < hi; ++n) s += hout[n * HID + c];
    int cnt = hi - lo;
    out[g * HID + c] = s / fmaxf((float)cnt, 1.0f);
}

extern "C" void kernel_launch(void* const* d_in, const int* in_sizes, int n_in,
                              void* d_out, int out_size, void* d_ws, size_t ws_size,
                              hipStream_t stream) {
    const int*   z       = (const int*)  d_in[0];
    const float* pos     = (const float*)d_in[1];
    const int*   batch   = (const int*)  d_in[2];
    const int*   ei      = (const int*)  d_in[3];
    const float* emb     = (const float*)d_in[4];
    const float* mlp1_w  = (const float*)d_in[5];
    const float* mlp1_b  = (const float*)d_in[6];
    const float* mlp2_w  = (const float*)d_in[7];
    const float* mlp2_b  = (const float*)d_in[8];
    const float* cl1_w   = (const float*)d_in[9];
    const float* cl2_w   = (const float*)d_in[10];
    const float* cl2_b   = (const float*)d_in[11];
    const float* lin_w   = (const float*)d_in[12];
    const float* lin_b   = (const float*)d_in[13];
    const float* out1_w  = (const float*)d_in[14];
    const float* out1_b  = (const float*)d_in[15];
    const float* out2_w  = (const float*)d_in[16];
    const float* out2_b  = (const float*)d_in[17];

    float* ws  = (float*)d_ws;
    float* h   = ws;                       // N*HID
    float* xh  = h   + N_NODES * HID;      // N*FILT
    float* agg = xh  + N_NODES * HID;      // N*FILT
    float* ew  = agg + N_NODES * HID;      // E

    k_embed<<<N_NODES * HID / 256, 256, 0, stream>>>(z, emb, h);
    k_ew<<<(N_EDGES + 255) / 256, 256, 0, stream>>>(pos, ei, ew);

    for (int i = 0; i < NL; ++i) {
        k_xh<<<256, 1024, 0, stream>>>(h, cl1_w + (size_t)i * HID * FILT, xh);
        hipMemsetAsync(agg, 0, (size_t)N_NODES * FILT * sizeof(float), stream);
        k_edge<<<256, 1024, 0, stream>>>(ew, ei, xh,
                                         mlp1_w + (size_t)i * NG * FILT,
                                         mlp1_b + (size_t)i * FILT,
                                         mlp2_w + (size_t)i * FILT * FILT,
                                         mlp2_b + (size_t)i * FILT,
                                         agg);
        k_node<true><<<256, 1024, 0, stream>>>(agg,
                                               cl2_w + (size_t)i * FILT * HID,
                                               cl2_b + (size_t)i * HID,
                                               lin_w + (size_t)i * HID * HID,
                                               lin_b + (size_t)i * HID,
                                               h, h);
    }
    // final MLP: xh <- ssp(h@out1+b1)@out2+b2
    k_node<false><<<256, 1024, 0, stream>>>(h, out1_w, out1_b, out2_w, out2_b,
                                            nullptr, xh);
    k_pool<<<N_GRAPHS, HID, 0, stream>>>(xh, batch, (float*)d_out);
}

// Round 2
// 7637.901 us; speedup vs baseline: 4.1754x; 4.1754x over previous
//
#include <hip/hip_runtime.h>
#include <math.h>

#define N_NODES 16384
#define N_EDGES 524288
#define N_GRAPHS 64
#define HID 128
#define FILT 128
#define NG 51
#define NL 6
#define RPB 8   // rows per block in fused edge kernel

__device__ __forceinline__ float ssp(float x) {
    float sp = (x > 20.0f) ? x : log1pf(__expf(x));
    return sp - 0.6931471805599453f;
}

__global__ void k_embed(const int* __restrict__ z, const float* __restrict__ emb,
                        float* __restrict__ h) {
    int i = blockIdx.x * blockDim.x + threadIdx.x;
    int n = i >> 7, c = i & 127;
    h[i] = emb[z[n] * HID + c];
}

// histogram of edge rows
__global__ void k_hist(const int* __restrict__ ei, int* __restrict__ cnt) {
    int e = blockIdx.x * blockDim.x + threadIdx.x;
    if (e < N_EDGES) atomicAdd(&cnt[ei[e]], 1);
}

// exclusive scan of 16384 counts -> rowptr[16385], wo (working offsets)
__global__ __launch_bounds__(1024) void k_scan(const int* __restrict__ cnt,
                                               int* __restrict__ rowptr,
                                               int* __restrict__ wo) {
    __shared__ int sums[1024];
    int t = threadIdx.x;
    int loc[16];
    int s = 0;
    #pragma unroll
    for (int i = 0; i < 16; ++i) { loc[i] = cnt[t * 16 + i]; s += loc[i]; }
    sums[t] = s;
    __syncthreads();
    for (int off = 1; off < 1024; off <<= 1) {
        int v = sums[t];
        int u = (t >= off) ? sums[t - off] : 0;
        __syncthreads();
        sums[t] = v + u;
        __syncthreads();
    }
    int ex = sums[t] - s;
    #pragma unroll
    for (int i = 0; i < 16; ++i) {
        rowptr[t * 16 + i] = ex;
        wo[t * 16 + i] = ex;
        ex += loc[i];
    }
    if (t == 1023) rowptr[16384] = ex;
}

// scatter edges into CSR order; also compute edge distance
__global__ void k_scatter(const int* __restrict__ ei, const float* __restrict__ pos,
                          int* __restrict__ wo, int* __restrict__ colp,
                          int* __restrict__ rowp, float* __restrict__ ewp) {
    int e = blockIdx.x * blockDim.x + threadIdx.x;
    if (e >= N_EDGES) return;
    int r = ei[e], c = ei[N_EDGES + e];
    int p = atomicAdd(&wo[r], 1);
    float dx = pos[r * 3 + 0] - pos[c * 3 + 0];
    float dy = pos[r * 3 + 1] - pos[c * 3 + 1];
    float dz = pos[r * 3 + 2] - pos[c * 3 + 2];
    colp[p] = c;
    rowp[p] = r;
    ewp[p] = sqrtf(dx * dx + dy * dy + dz * dz);
}

// xh = h @ cl1_w[i]
__global__ __launch_bounds__(1024) void k_xh(const float* __restrict__ h,
                                             const float* __restrict__ W,
                                             float* __restrict__ xh) {
    __shared__ float Ws[HID * FILT];
    for (int i = threadIdx.x; i < HID * FILT / 4; i += 1024)
        ((float4*)Ws)[i] = ((const float4*)W)[i];
    __syncthreads();
    int g = threadIdx.x >> 7, c = threadIdx.x & 127;
    for (int n = blockIdx.x * 8 + g; n < N_NODES; n += gridDim.x * 8) {
        const float* hr = h + n * HID;
        float acc = 0.f;
        #pragma unroll 8
        for (int k = 0; k < HID; ++k) acc += hr[k] * Ws[k * FILT + c];
        xh[n * FILT + c] = acc;
    }
}

// Fused per-edge filter MLP + modulate + CSR aggregation (no global atomics).
// Block owns rows [r0, r0+RPB); processes its edges in tiles of 128.
// Threads: 1024 = 32 edge-groups (e0 = (t&31)*4) x 32 ch-groups (c0 = (t>>5)*4).
__global__ __launch_bounds__(1024) void k_fused(
    const float* __restrict__ ewp, const int* __restrict__ colp,
    const int* __restrict__ rowp, const int* __restrict__ rowptr,
    const float* __restrict__ xh,
    const float* __restrict__ W1, const float* __restrict__ B1,
    const float* __restrict__ W2, const float* __restrict__ B2,
    float* __restrict__ agg)
{
    __shared__ float W1s[NG * FILT];        // 26112 B
    __shared__ float W2s[FILT * FILT];      // 65536 B
    __shared__ float buf[FILT * FILT];      // 65536 B : eas_t[k][e] then ts_t[k][e]
    __shared__ float Cs[128];
    __shared__ float ews[128];
    __shared__ float aggs[RPB * FILT];      // 4096 B
    const int tid = threadIdx.x;
    for (int i = tid; i < NG * FILT / 4; i += 1024)
        ((float4*)W1s)[i] = ((const float4*)W1)[i];
    for (int i = tid; i < FILT * FILT / 4; i += 1024)
        ((float4*)W2s)[i] = ((const float4*)W2)[i];
    for (int i = tid; i < RPB * FILT; i += 1024) aggs[i] = 0.f;
    const int e0 = (tid & 31) * 4;
    const int c0 = (tid >> 5) * 4;
    const float4 b1v = *(const float4*)(B1 + c0);
    const float4 b2v = *(const float4*)(B2 + c0);
    const int r0 = blockIdx.x * RPB;
    const int estart = rowptr[r0], eend = rowptr[r0 + RPB];
    __syncthreads();

    for (int t0 = estart; t0 < eend; t0 += 128) {
        if (tid < 128) {
            int e = t0 + tid;
            float w = (e < eend) ? ewp[e] : 1.0e9f;
            ews[tid] = w;
            Cs[tid] = (e < eend) ? 0.5f * (__cosf(w * 0.31415926535f) + 1.0f) : 0.f;
        }
        __syncthreads();
        // gaussians: eas_t[k][e]
        for (int idx = tid; idx < NG * 128; idx += 1024) {
            int k = idx >> 7, e = idx & 127;
            float d = ews[e] - 0.2f * (float)k;
            buf[idx] = __expf(-12.5f * d * d);
        }
        __syncthreads();
        // MLP1: acc[i=edge][j=ch]
        float acc[4][4];
        #pragma unroll
        for (int i = 0; i < 4; ++i)
            #pragma unroll
            for (int j = 0; j < 4; ++j)
                acc[i][j] = ((const float*)&b1v)[j];
        #pragma unroll 3
        for (int k = 0; k < NG; ++k) {
            float4 a = *(float4*)&buf[k * 128 + e0];
            float4 b = *(float4*)&W1s[k * FILT + c0];
            #pragma unroll
            for (int i = 0; i < 4; ++i)
                #pragma unroll
                for (int j = 0; j < 4; ++j)
                    acc[i][j] += ((float*)&a)[i] * ((float*)&b)[j];
        }
        __syncthreads();   // all eas reads done
        // ssp, stage ts_t[c][e]
        #pragma unroll
        for (int j = 0; j < 4; ++j) {
            float4 w;
            ((float*)&w)[0] = ssp(acc[0][j]);
            ((float*)&w)[1] = ssp(acc[1][j]);
            ((float*)&w)[2] = ssp(acc[2][j]);
            ((float*)&w)[3] = ssp(acc[3][j]);
            *(float4*)&buf[(c0 + j) * 128 + e0] = w;
        }
        __syncthreads();
        // MLP2
        float acc2[4][4];
        #pragma unroll
        for (int i = 0; i < 4; ++i)
            #pragma unroll
            for (int j = 0; j < 4; ++j)
                acc2[i][j] = ((const float*)&b2v)[j];
        #pragma unroll 2
        for (int k = 0; k < FILT; ++k) {
            float4 a = *(float4*)&buf[k * 128 + e0];
            float4 b = *(float4*)&W2s[k * FILT + c0];
            #pragma unroll
            for (int i = 0; i < 4; ++i)
                #pragma unroll
                for (int j = 0; j < 4; ++j)
                    acc2[i][j] += ((float*)&a)[i] * ((float*)&b)[j];
        }
        // epilogue: msg = W * C * xh[col], accumulate into LDS agg tile
        #pragma unroll
        for (int i = 0; i < 4; ++i) {
            int e = t0 + e0 + i;
            if (e < eend) {
                int col = colp[e];
                int lr = rowp[e] - r0;
                float Cv = Cs[e0 + i];
                float4 xv = *(const float4*)&xh[col * FILT + c0];
                #pragma unroll
                for (int j = 0; j < 4; ++j) {
                    float v = acc2[i][j] * Cv * ((float*)&xv)[j];
                    atomicAdd(&aggs[lr * FILT + c0 + j], v);
                }
            }
        }
        __syncthreads();
    }
    // flush owned rows
    for (int i = tid; i < RPB * FILT; i += 1024)
        agg[r0 * FILT + i] = aggs[i];
}

// Fused node MLP: out = ssp(X@W1 + B1) @ W2 + B2 ; Hout = (RESID ? Hin + out : out)
template<bool RESID>
__global__ __launch_bounds__(1024) void k_node(
    const float* __restrict__ X,
    const float* __restrict__ W1, const float* __restrict__ B1,
    const float* __restrict__ W2, const float* __restrict__ B2,
    const float* __restrict__ Hin, float* __restrict__ Hout)
{
    __shared__ float W1s[HID * FILT];
    __shared__ float W2s[FILT * HID];
    __shared__ float ts[32 * FILT];
    for (int i = threadIdx.x; i < HID * FILT / 4; i += 1024) {
        ((float4*)W1s)[i] = ((const float4*)W1)[i];
        ((float4*)W2s)[i] = ((const float4*)W2)[i];
    }
    __syncthreads();
    const int g = threadIdx.x >> 7;
    const int c = threadIdx.x & 127;
    for (int tile = blockIdx.x; tile < N_NODES / 32; tile += gridDim.x) {
        int n0 = tile * 32 + g * 4;
        float acc[4];
        #pragma unroll
        for (int j = 0; j < 4; ++j) acc[j] = B1[c];
        for (int k = 0; k < HID; ++k) {
            float w = W1s[k * FILT + c];
            #pragma unroll
            for (int j = 0; j < 4; ++j) acc[j] += X[(n0 + j) * HID + k] * w;
        }
        #pragma unroll
        for (int j = 0; j < 4; ++j) ts[(g * 4 + j) * FILT + c] = ssp(acc[j]);
        __syncthreads();
        #pragma unroll
        for (int j = 0; j < 4; ++j) acc[j] = B2[c];
        for (int k = 0; k < FILT; ++k) {
            float w = W2s[k * HID + c];
            #pragma unroll
            for (int j = 0; j < 4; ++j) acc[j] += ts[(g * 4 + j) * FILT + k] * w;
        }
        #pragma unroll
        for (int j = 0; j < 4; ++j) {
            float o = acc[j];
            if (RESID) o += Hin[(n0 + j) * HID + c];
            Hout[(n0 + j) * HID + c] = o;
        }
        __syncthreads();
    }
}

__global__ void k_pool(const float* __restrict__ hout, const int* __restrict__ batch,
                       float* __restrict__ out) {
    int g = blockIdx.x;
    int c = threadIdx.x;
    int a = 0, b = N_NODES;
    while (a < b) { int m = (a + b) >> 1; if (batch[m] < g) a = m + 1; else b = m; }
    int lo = a;
    b = N_NODES;
    while (a < b) { int m = (a + b) >> 1; if (batch[m] < g + 1) a = m + 1; else b = m; }
    int hi = a;
    float s = 0.f;
    for (int n = lo; n < hi; ++n) s += hout[n * HID + c];
    int cnt = hi - lo;
    out[g * HID + c] = s / fmaxf((float)cnt, 1.0f);
}

extern "C" void kernel_launch(void* const* d_in, const int* in_sizes, int n_in,
                              void* d_out, int out_size, void* d_ws, size_t ws_size,
                              hipStream_t stream) {
    const int*   z       = (const int*)  d_in[0];
    const float* pos     = (const float*)d_in[1];
    const int*   batch   = (const int*)  d_in[2];
    const int*   ei      = (const int*)  d_in[3];
    const float* emb     = (const float*)d_in[4];
    const float* mlp1_w  = (const float*)d_in[5];
    const float* mlp1_b  = (const float*)d_in[6];
    const float* mlp2_w  = (const float*)d_in[7];
    const float* mlp2_b  = (const float*)d_in[8];
    const float* cl1_w   = (const float*)d_in[9];
    const float* cl2_w   = (const float*)d_in[10];
    const float* cl2_b   = (const float*)d_in[11];
    const float* lin_w   = (const float*)d_in[12];
    const float* lin_b   = (const float*)d_in[13];
    const float* out1_w  = (const float*)d_in[14];
    const float* out1_b  = (const float*)d_in[15];
    const float* out2_w  = (const float*)d_in[16];
    const float* out2_b  = (const float*)d_in[17];

    float* ws     = (float*)d_ws;
    float* h      = ws;                        // 2097152
    float* xh     = h    + (size_t)N_NODES * HID;
    float* agg    = xh   + (size_t)N_NODES * HID;
    float* ewp    = agg  + (size_t)N_NODES * HID;
    int*   colp   = (int*)(ewp + N_EDGES);
    int*   rowp   = colp + N_EDGES;
    int*   cnt    = rowp + N_EDGES;
    int*   rowptr = cnt + N_NODES;
    int*   wo     = rowptr + N_NODES + 1;

    hipMemsetAsync(cnt, 0, N_NODES * sizeof(int), stream);
    k_embed<<<N_NODES * HID / 256, 256, 0, stream>>>(z, emb, h);
    k_hist<<<N_EDGES / 256, 256, 0, stream>>>(ei, cnt);
    k_scan<<<1, 1024, 0, stream>>>(cnt, rowptr, wo);
    k_scatter<<<N_EDGES / 256, 256, 0, stream>>>(ei, pos, wo, colp, rowp, ewp);

    for (int i = 0; i < NL; ++i) {
        k_xh<<<256, 1024, 0, stream>>>(h, cl1_w + (size_t)i * HID * FILT, xh);
        k_fused<<<N_NODES / RPB, 1024, 0, stream>>>(
            ewp, colp, rowp, rowptr, xh,
            mlp1_w + (size_t)i * NG * FILT,
            mlp1_b + (size_t)i * FILT,
            mlp2_w + (size_t)i * FILT * FILT,
            mlp2_b + (size_t)i * FILT,
            agg);
        k_node<true><<<256, 1024, 0, stream>>>(agg,
                                               cl2_w + (size_t)i * FILT * HID,
                                               cl2_b + (size_t)i * HID,
                                               lin_w + (size_t)i * HID * HID,
                                               lin_b + (size_t)i * HID,
                                               h, h);
    }
    k_node<false><<<256, 1024, 0, stream>>>(h, out1_w, out1_b, out2_w, out2_b,
                                            nullptr, xh);
    k_pool<<<N_GRAPHS, HID, 0, stream>>>(xh, batch, (float*)d_out);
}

// Round 3
// 6574.391 us; speedup vs baseline: 4.8509x; 1.1618x over previous
//
#include <hip/hip_runtime.h>
#include <math.h>

#define N_NODES 16384
#define N_EDGES 524288
#define N_GRAPHS 64
#define HID 128
#define FILT 128
#define NG 51
#define NL 6
#define RPB 8    // rows per block in fused edge kernel
#define ET 64    // edge tile

__device__ __forceinline__ float ssp(float x) {
    float sp = (x > 20.0f) ? x : log1pf(__expf(x));
    return sp - 0.6931471805599453f;
}

__global__ void k_embed(const int* __restrict__ z, const float* __restrict__ emb,
                        float* __restrict__ h) {
    int i = blockIdx.x * blockDim.x + threadIdx.x;
    int n = i >> 7, c = i & 127;
    h[i] = emb[z[n] * HID + c];
}

// histogram of edge rows
__global__ void k_hist(const int* __restrict__ ei, int* __restrict__ cnt) {
    int e = blockIdx.x * blockDim.x + threadIdx.x;
    if (e < N_EDGES) atomicAdd(&cnt[ei[e]], 1);
}

// exclusive scan of 16384 counts -> rowptr[16385], wo (working offsets)
__global__ __launch_bounds__(1024) void k_scan(const int* __restrict__ cnt,
                                               int* __restrict__ rowptr,
                                               int* __restrict__ wo) {
    __shared__ int sums[1024];
    int t = threadIdx.x;
    int loc[16];
    int s = 0;
    #pragma unroll
    for (int i = 0; i < 16; ++i) { loc[i] = cnt[t * 16 + i]; s += loc[i]; }
    sums[t] = s;
    __syncthreads();
    for (int off = 1; off < 1024; off <<= 1) {
        int v = sums[t];
        int u = (t >= off) ? sums[t - off] : 0;
        __syncthreads();
        sums[t] = v + u;
        __syncthreads();
    }
    int ex = sums[t] - s;
    #pragma unroll
    for (int i = 0; i < 16; ++i) {
        rowptr[t * 16 + i] = ex;
        wo[t * 16 + i] = ex;
        ex += loc[i];
    }
    if (t == 1023) rowptr[16384] = ex;
}

// scatter edges into CSR order; also compute edge distance
__global__ void k_scatter(const int* __restrict__ ei, const float* __restrict__ pos,
                          int* __restrict__ wo, int* __restrict__ colp,
                          int* __restrict__ rowp, float* __restrict__ ewp) {
    int e = blockIdx.x * blockDim.x + threadIdx.x;
    if (e >= N_EDGES) return;
    int r = ei[e], c = ei[N_EDGES + e];
    int p = atomicAdd(&wo[r], 1);
    float dx = pos[r * 3 + 0] - pos[c * 3 + 0];
    float dy = pos[r * 3 + 1] - pos[c * 3 + 1];
    float dz = pos[r * 3 + 2] - pos[c * 3 + 2];
    colp[p] = c;
    rowp[p] = r;
    ewp[p] = sqrtf(dx * dx + dy * dy + dz * dz);
}

// xh = h @ cl1_w[i]
__global__ __launch_bounds__(1024) void k_xh(const float* __restrict__ h,
                                             const float* __restrict__ W,
                                             float* __restrict__ xh) {
    __shared__ float Ws[HID * FILT];
    for (int i = threadIdx.x; i < HID * FILT / 4; i += 1024)
        ((float4*)Ws)[i] = ((const float4*)W)[i];
    __syncthreads();
    int g = threadIdx.x >> 7, c = threadIdx.x & 127;
    for (int n = blockIdx.x * 8 + g; n < N_NODES; n += gridDim.x * 8) {
        const float* hr = h + n * HID;
        float acc = 0.f;
        #pragma unroll 8
        for (int k = 0; k < HID; ++k) acc += hr[k] * Ws[k * FILT + c];
        xh[n * FILT + c] = acc;
    }
}

// Fused per-edge filter MLP + modulate + CSR aggregation.
// Weights read from GLOBAL (L1/L2-hot, shared by all blocks) -> small LDS,
// 4 blocks/CU. Block owns rows [r0, r0+RPB); edge tiles of ET=64.
// Threads: 512 = 16 edge-groups (e0=(t&15)*4) x 32 ch-groups (c0=(t>>4)*4).
__global__ __launch_bounds__(512, 8) void k_fused(
    const float* __restrict__ ewp, const int* __restrict__ colp,
    const int* __restrict__ rowp, const int* __restrict__ rowptr,
    const float* __restrict__ xh,
    const float* __restrict__ W1, const float* __restrict__ B1,
    const float* __restrict__ W2, const float* __restrict__ B2,
    float* __restrict__ agg)
{
    __shared__ float buf[FILT * ET];     // 32768 B: eas_t[k][e] then ts_t[c][e]
    __shared__ float Cs[ET];
    __shared__ float aggs[RPB * FILT];   // 4096 B
    const int tid = threadIdx.x;
    for (int i = tid; i < RPB * FILT; i += 512) aggs[i] = 0.f;
    const int e0 = (tid & 15) * 4;
    const int c0 = (tid >> 4) * 4;
    const float4 b1v = *(const float4*)(B1 + c0);
    const float4 b2v = *(const float4*)(B2 + c0);
    const int r0 = blockIdx.x * RPB;
    const int estart = rowptr[r0], eend = rowptr[r0 + RPB];
    __syncthreads();

    for (int t0 = estart; t0 < eend; t0 += ET) {
        // gaussians eas_t[k][e] (read ew straight from global; L1-broadcast)
        for (int idx = tid; idx < NG * ET; idx += 512) {
            int k = idx >> 6, e = idx & (ET - 1);
            float w = (t0 + e < eend) ? ewp[t0 + e] : 1.0e9f;
            float d = w - 0.2f * (float)k;
            buf[idx] = __expf(-12.5f * d * d);
        }
        if (tid < ET) {
            int e = t0 + tid;
            Cs[tid] = (e < eend) ? 0.5f * (__cosf(ewp[e] * 0.31415926535f) + 1.0f) : 0.f;
        }
        __syncthreads();
        // MLP1: acc[i=edge][j=ch], A from LDS, B from global
        float acc[4][4];
        #pragma unroll
        for (int i = 0; i < 4; ++i)
            #pragma unroll
            for (int j = 0; j < 4; ++j)
                acc[i][j] = ((const float*)&b1v)[j];
        #pragma unroll 3
        for (int k = 0; k < NG; ++k) {
            float4 a = *(float4*)&buf[k * ET + e0];
            float4 b = *(const float4*)&W1[k * FILT + c0];
            #pragma unroll
            for (int i = 0; i < 4; ++i)
                #pragma unroll
                for (int j = 0; j < 4; ++j)
                    acc[i][j] += ((float*)&a)[i] * ((float*)&b)[j];
        }
        __syncthreads();   // eas reads done before overwriting buf with ts
        #pragma unroll
        for (int j = 0; j < 4; ++j) {
            float4 w;
            ((float*)&w)[0] = ssp(acc[0][j]);
            ((float*)&w)[1] = ssp(acc[1][j]);
            ((float*)&w)[2] = ssp(acc[2][j]);
            ((float*)&w)[3] = ssp(acc[3][j]);
            *(float4*)&buf[(c0 + j) * ET + e0] = w;
        }
        __syncthreads();
        // MLP2
        float acc2[4][4];
        #pragma unroll
        for (int i = 0; i < 4; ++i)
            #pragma unroll
            for (int j = 0; j < 4; ++j)
                acc2[i][j] = ((const float*)&b2v)[j];
        #pragma unroll 4
        for (int k = 0; k < FILT; ++k) {
            float4 a = *(float4*)&buf[k * ET + e0];
            float4 b = *(const float4*)&W2[k * FILT + c0];
            #pragma unroll
            for (int i = 0; i < 4; ++i)
                #pragma unroll
                for (int j = 0; j < 4; ++j)
                    acc2[i][j] += ((float*)&a)[i] * ((float*)&b)[j];
        }
        // epilogue: msg = W * C * xh[col] -> LDS agg tile
        #pragma unroll
        for (int i = 0; i < 4; ++i) {
            int e = t0 + e0 + i;
            if (e < eend) {
                int col = colp[e];
                int lr = rowp[e] - r0;
                float Cv = Cs[e0 + i];
                float4 xv = *(const float4*)&xh[col * FILT + c0];
                #pragma unroll
                for (int j = 0; j < 4; ++j) {
                    float v = acc2[i][j] * Cv * ((float*)&xv)[j];
                    atomicAdd(&aggs[lr * FILT + c0 + j], v);
                }
            }
        }
        __syncthreads();
    }
    for (int i = tid; i < RPB * FILT; i += 512)
        agg[r0 * FILT + i] = aggs[i];
}

// Fused node MLP: out = ssp(X@W1 + B1) @ W2 + B2 ; Hout = (RESID ? Hin + out : out)
template<bool RESID>
__global__ __launch_bounds__(1024) void k_node(
    const float* __restrict__ X,
    const float* __restrict__ W1, const float* __restrict__ B1,
    const float* __restrict__ W2, const float* __restrict__ B2,
    const float* __restrict__ Hin, float* __restrict__ Hout)
{
    __shared__ float W1s[HID * FILT];
    __shared__ float W2s[FILT * HID];
    __shared__ float ts[32 * FILT];
    for (int i = threadIdx.x; i < HID * FILT / 4; i += 1024) {
        ((float4*)W1s)[i] = ((const float4*)W1)[i];
        ((float4*)W2s)[i] = ((const float4*)W2)[i];
    }
    __syncthreads();
    const int g = threadIdx.x >> 7;
    const int c = threadIdx.x & 127;
    for (int tile = blockIdx.x; tile < N_NODES / 32; tile += gridDim.x) {
        int n0 = tile * 32 + g * 4;
        float acc[4];
        #pragma unroll
        for (int j = 0; j < 4; ++j) acc[j] = B1[c];
        for (int k = 0; k < HID; ++k) {
            float w = W1s[k * FILT + c];
            #pragma unroll
            for (int j = 0; j < 4; ++j) acc[j] += X[(n0 + j) * HID + k] * w;
        }
        #pragma unroll
        for (int j = 0; j < 4; ++j) ts[(g * 4 + j) * FILT + c] = ssp(acc[j]);
        __syncthreads();
        #pragma unroll
        for (int j = 0; j < 4; ++j) acc[j] = B2[c];
        for (int k = 0; k < FILT; ++k) {
            float w = W2s[k * HID + c];
            #pragma unroll
            for (int j = 0; j < 4; ++j) acc[j] += ts[(g * 4 + j) * FILT + k] * w;
        }
        #pragma unroll
        for (int j = 0; j < 4; ++j) {
            float o = acc[j];
            if (RESID) o += Hin[(n0 + j) * HID + c];
            Hout[(n0 + j) * HID + c] = o;
        }
        __syncthreads();
    }
}

__global__ void k_pool(const float* __restrict__ hout, const int* __restrict__ batch,
                       float* __restrict__ out) {
    int g = blockIdx.x;
    int c = threadIdx.x;
    int a = 0, b = N_NODES;
    while (a < b) { int m = (a + b) >> 1; if (batch[m] < g) a = m + 1; else b = m; }
    int lo = a;
    b = N_NODES;
    while (a < b) { int m = (a + b) >> 1; if (batch[m] < g + 1) a = m + 1; else b = m; }
    int hi = a;
    float s = 0.f;
    for (int n = lo; n < hi; ++n) s += hout[n * HID + c];
    int cnt = hi - lo;
    out[g * HID + c] = s / fmaxf((float)cnt, 1.0f);
}

extern "C" void kernel_launch(void* const* d_in, const int* in_sizes, int n_in,
                              void* d_out, int out_size, void* d_ws, size_t ws_size,
                              hipStream_t stream) {
    const int*   z       = (const int*)  d_in[0];
    const float* pos     = (const float*)d_in[1];
    const int*   batch   = (const int*)  d_in[2];
    const int*   ei      = (const int*)  d_in[3];
    const float* emb     = (const float*)d_in[4];
    const float* mlp1_w  = (const float*)d_in[5];
    const float* mlp1_b  = (const float*)d_in[6];
    const float* mlp2_w  = (const float*)d_in[7];
    const float* mlp2_b  = (const float*)d_in[8];
    const float* cl1_w   = (const float*)d_in[9];
    const float* cl2_w   = (const float*)d_in[10];
    const float* cl2_b   = (const float*)d_in[11];
    const float* lin_w   = (const float*)d_in[12];
    const float* lin_b   = (const float*)d_in[13];
    const float* out1_w  = (const float*)d_in[14];
    const float* out1_b  = (const float*)d_in[15];
    const float* out2_w  = (const float*)d_in[16];
    const float* out2_b  = (const float*)d_in[17];

    float* ws     = (float*)d_ws;
    float* h      = ws;
    float* xh     = h    + (size_t)N_NODES * HID;
    float* agg    = xh   + (size_t)N_NODES * HID;
    float* ewp    = agg  + (size_t)N_NODES * HID;
    int*   colp   = (int*)(ewp + N_EDGES);
    int*   rowp   = colp + N_EDGES;
    int*   cnt    = rowp + N_EDGES;
    int*   rowptr = cnt + N_NODES;
    int*   wo     = rowptr + N_NODES + 1;

    hipMemsetAsync(cnt, 0, N_NODES * sizeof(int), stream);
    k_embed<<<N_NODES * HID / 256, 256, 0, stream>>>(z, emb, h);
    k_hist<<<N_EDGES / 256, 256, 0, stream>>>(ei, cnt);
    k_scan<<<1, 1024, 0, stream>>>(cnt, rowptr, wo);
    k_scatter<<<N_EDGES / 256, 256, 0, stream>>>(ei, pos, wo, colp, rowp, ewp);

    for (int i = 0; i < NL; ++i) {
        k_xh<<<256, 1024, 0, stream>>>(h, cl1_w + (size_t)i * HID * FILT, xh);
        k_fused<<<N_NODES / RPB, 512, 0, stream>>>(
            ewp, colp, rowp, rowptr, xh,
            mlp1_w + (size_t)i * NG * FILT,
            mlp1_b + (size_t)i * FILT,
            mlp2_w + (size_t)i * FILT * FILT,
            mlp2_b + (size_t)i * FILT,
            agg);
        k_node<true><<<256, 1024, 0, stream>>>(agg,
                                               cl2_w + (size_t)i * FILT * HID,
                                               cl2_b + (size_t)i * HID,
                                               lin_w + (size_t)i * HID * HID,
                                               lin_b + (size_t)i * HID,
                                               h, h);
    }
    k_node<false><<<256, 1024, 0, stream>>>(h, out1_w, out1_b, out2_w, out2_b,
                                            nullptr, xh);
    k_pool<<<N_GRAPHS, HID, 0, stream>>>(xh, batch, (float*)d_out);
}

// Round 4
// 2856.101 us; speedup vs baseline: 11.1661x; 2.3019x over previous
//
#include <hip/hip_runtime.h>
#include <math.h>

#define N_NODES 16384
#define N_EDGES 524288
#define N_GRAPHS 64
#define HID 128
#define FILT 128
#define NG 51
#define NL 6
#define RPB 8        // rows per block in edge kernel
#define TROWS 2048   // filter-table resolution
#define DMAX 8.66025404f          // 5*sqrt(3), max possible distance
#define DSTEP (DMAX / (TROWS - 1))
#define INV_DSTEP ((TROWS - 1) / DMAX)

__device__ __forceinline__ float ssp(float x) {
    float sp = (x > 20.0f) ? x : log1pf(__expf(x));
    return sp - 0.6931471805599453f;
}

__global__ void k_embed(const int* __restrict__ z, const float* __restrict__ emb,
                        float* __restrict__ h) {
    int i = blockIdx.x * blockDim.x + threadIdx.x;
    int n = i >> 7, c = i & 127;
    h[i] = emb[z[n] * HID + c];
}

__global__ void k_hist(const int* __restrict__ ei, int* __restrict__ cnt) {
    int e = blockIdx.x * blockDim.x + threadIdx.x;
    if (e < N_EDGES) atomicAdd(&cnt[ei[e]], 1);
}

__global__ __launch_bounds__(1024) void k_scan(const int* __restrict__ cnt,
                                               int* __restrict__ rowptr,
                                               int* __restrict__ wo) {
    __shared__ int sums[1024];
    int t = threadIdx.x;
    int loc[16];
    int s = 0;
    #pragma unroll
    for (int i = 0; i < 16; ++i) { loc[i] = cnt[t * 16 + i]; s += loc[i]; }
    sums[t] = s;
    __syncthreads();
    for (int off = 1; off < 1024; off <<= 1) {
        int v = sums[t];
        int u = (t >= off) ? sums[t - off] : 0;
        __syncthreads();
        sums[t] = v + u;
        __syncthreads();
    }
    int ex = sums[t] - s;
    #pragma unroll
    for (int i = 0; i < 16; ++i) {
        rowptr[t * 16 + i] = ex;
        wo[t * 16 + i] = ex;
        ex += loc[i];
    }
    if (t == 1023) rowptr[16384] = ex;
}

__global__ void k_scatter(const int* __restrict__ ei, const float* __restrict__ pos,
                          int* __restrict__ wo, int* __restrict__ colp,
                          int* __restrict__ rowp, float* __restrict__ ewp) {
    int e = blockIdx.x * blockDim.x + threadIdx.x;
    if (e >= N_EDGES) return;
    int r = ei[e], c = ei[N_EDGES + e];
    int p = atomicAdd(&wo[r], 1);
    float dx = pos[r * 3 + 0] - pos[c * 3 + 0];
    float dy = pos[r * 3 + 1] - pos[c * 3 + 1];
    float dz = pos[r * 3 + 2] - pos[c * 3 + 2];
    colp[p] = c;
    rowp[p] = r;
    ewp[p] = sqrtf(dx * dx + dy * dy + dz * dz);
}

// Build the filter tables: ftab[layer][i][c] = (ssp(gauss(d_i)@W1+b1)@W2+b2)[c] * C(d_i)
// d_i = i*DSTEP. One block per (layer, 64-row tile): grid = NL*32.
// 512 threads = 16 row-groups (e0) x 32 ch-groups (c0).
__global__ __launch_bounds__(512) void k_tab(
    const float* __restrict__ mlp1_w, const float* __restrict__ mlp1_b,
    const float* __restrict__ mlp2_w, const float* __restrict__ mlp2_b,
    float* __restrict__ ftab)
{
    const int layer = blockIdx.x >> 5;
    const int tile  = blockIdx.x & 31;
    const float* W1 = mlp1_w + (size_t)layer * NG * FILT;
    const float* B1 = mlp1_b + (size_t)layer * FILT;
    const float* W2 = mlp2_w + (size_t)layer * FILT * FILT;
    const float* B2 = mlp2_b + (size_t)layer * FILT;
    float* out = ftab + (size_t)layer * TROWS * FILT + (size_t)tile * 64 * FILT;
    __shared__ float buf[FILT * 64];   // gauss[k][e] then ts[c][e]
    const int tid = threadIdx.x;
    const int e0 = (tid & 15) * 4;
    const int c0 = (tid >> 4) * 4;
    // gaussians
    for (int idx = tid; idx < NG * 64; idx += 512) {
        int k = idx >> 6, e = idx & 63;
        float d = (float)(tile * 64 + e) * DSTEP;
        float dd = d - 0.2f * (float)k;
        buf[idx] = __expf(-12.5f * dd * dd);
    }
    __syncthreads();
    float acc[4][4];
    #pragma unroll
    for (int i = 0; i < 4; ++i)
        #pragma unroll
        for (int j = 0; j < 4; ++j) acc[i][j] = B1[c0 + j];
    for (int k = 0; k < NG; ++k) {
        float4 a = *(float4*)&buf[k * 64 + e0];
        float4 b = *(const float4*)&W1[k * FILT + c0];
        #pragma unroll
        for (int i = 0; i < 4; ++i)
            #pragma unroll
            for (int j = 0; j < 4; ++j)
                acc[i][j] += ((float*)&a)[i] * ((float*)&b)[j];
    }
    __syncthreads();
    #pragma unroll
    for (int j = 0; j < 4; ++j) {
        float4 w;
        ((float*)&w)[0] = ssp(acc[0][j]);
        ((float*)&w)[1] = ssp(acc[1][j]);
        ((float*)&w)[2] = ssp(acc[2][j]);
        ((float*)&w)[3] = ssp(acc[3][j]);
        *(float4*)&buf[(c0 + j) * 64 + e0] = w;
    }
    __syncthreads();
    float acc2[4][4];
    #pragma unroll
    for (int i = 0; i < 4; ++i)
        #pragma unroll
        for (int j = 0; j < 4; ++j) acc2[i][j] = B2[c0 + j];
    for (int k = 0; k < FILT; ++k) {
        float4 a = *(float4*)&buf[k * 64 + e0];
        float4 b = *(const float4*)&W2[k * FILT + c0];
        #pragma unroll
        for (int i = 0; i < 4; ++i)
            #pragma unroll
            for (int j = 0; j < 4; ++j)
                acc2[i][j] += ((float*)&a)[i] * ((float*)&b)[j];
    }
    #pragma unroll
    for (int i = 0; i < 4; ++i) {
        int r = tile * 64 + e0 + i;
        float d = (float)r * DSTEP;
        float C = 0.5f * (__cosf(d * 0.31415926535f) + 1.0f);
        #pragma unroll
        for (int j = 0; j < 4; ++j)
            out[(e0 + i) * FILT + c0 + j] = acc2[i][j] * C;
    }
}

// Per-edge: W = lerp(tab, d) ; msg = W * xh[col] ; LDS-aggregate into owned rows.
// Block owns rows [r0, r0+RPB). 512 threads = 16 edges x 32 ch-groups.
__global__ __launch_bounds__(512, 8) void k_edge2(
    const float* __restrict__ ewp, const int* __restrict__ colp,
    const int* __restrict__ rowp, const int* __restrict__ rowptr,
    const float* __restrict__ xh, const float* __restrict__ tab,
    float* __restrict__ agg)
{
    __shared__ float aggs[RPB * FILT];   // 4 KB
    const int tid = threadIdx.x;
    for (int i = tid; i < RPB * FILT; i += 512) aggs[i] = 0.f;
    const int c0 = (tid & 31) * 4;
    const int eg = tid >> 5;             // 0..15
    const int r0 = blockIdx.x * RPB;
    const int estart = rowptr[r0], eend = rowptr[r0 + RPB];
    __syncthreads();
    for (int eb = estart; eb < eend; eb += 16) {
        int e = eb + eg;
        if (e < eend) {
            float d = ewp[e];
            int col = colp[e];
            int lr = rowp[e] - r0;
            float u = d * INV_DSTEP;
            int i0 = (int)u;
            i0 = min(i0, TROWS - 2);
            float f = u - (float)i0;
            float4 t0 = *(const float4*)&tab[(size_t)i0 * FILT + c0];
            float4 t1 = *(const float4*)&tab[(size_t)(i0 + 1) * FILT + c0];
            float4 xv = *(const float4*)&xh[(size_t)col * FILT + c0];
            #pragma unroll
            for (int j = 0; j < 4; ++j) {
                float w = fmaf(f, ((float*)&t1)[j] - ((float*)&t0)[j], ((float*)&t0)[j]);
                atomicAdd(&aggs[lr * FILT + c0 + j], w * ((float*)&xv)[j]);
            }
        }
    }
    __syncthreads();
    for (int i = tid; i < RPB * FILT; i += 512)
        agg[r0 * FILT + i] = aggs[i];
}

// xh = h @ cl1_w[i]
__global__ __launch_bounds__(1024) void k_xh(const float* __restrict__ h,
                                             const float* __restrict__ W,
                                             float* __restrict__ xh) {
    __shared__ float Ws[HID * FILT];
    for (int i = threadIdx.x; i < HID * FILT / 4; i += 1024)
        ((float4*)Ws)[i] = ((const float4*)W)[i];
    __syncthreads();
    int g = threadIdx.x >> 7, c = threadIdx.x & 127;
    for (int n = blockIdx.x * 8 + g; n < N_NODES; n += gridDim.x * 8) {
        const float* hr = h + n * HID;
        float acc = 0.f;
        #pragma unroll 8
        for (int k = 0; k < HID; ++k) acc += hr[k] * Ws[k * FILT + c];
        xh[n * FILT + c] = acc;
    }
}

// Fused node MLP: out = ssp(X@W1 + B1) @ W2 + B2 ; Hout = (RESID ? Hin + out : out)
template<bool RESID>
__global__ __launch_bounds__(1024) void k_node(
    const float* __restrict__ X,
    const float* __restrict__ W1, const float* __restrict__ B1,
    const float* __restrict__ W2, const float* __restrict__ B2,
    const float* __restrict__ Hin, float* __restrict__ Hout)
{
    __shared__ float W1s[HID * FILT];
    __shared__ float W2s[FILT * HID];
    __shared__ float ts[32 * FILT];
    for (int i = threadIdx.x; i < HID * FILT / 4; i += 1024) {
        ((float4*)W1s)[i] = ((const float4*)W1)[i];
        ((float4*)W2s)[i] = ((const float4*)W2)[i];
    }
    __syncthreads();
    const int g = threadIdx.x >> 7;
    const int c = threadIdx.x & 127;
    for (int tile = blockIdx.x; tile < N_NODES / 32; tile += gridDim.x) {
        int n0 = tile * 32 + g * 4;
        float acc[4];
        #pragma unroll
        for (int j = 0; j < 4; ++j) acc[j] = B1[c];
        for (int k = 0; k < HID; ++k) {
            float w = W1s[k * FILT + c];
            #pragma unroll
            for (int j = 0; j < 4; ++j) acc[j] += X[(n0 + j) * HID + k] * w;
        }
        #pragma unroll
        for (int j = 0; j < 4; ++j) ts[(g * 4 + j) * FILT + c] = ssp(acc[j]);
        __syncthreads();
        #pragma unroll
        for (int j = 0; j < 4; ++j) acc[j] = B2[c];
        for (int k = 0; k < FILT; ++k) {
            float w = W2s[k * HID + c];
            #pragma unroll
            for (int j = 0; j < 4; ++j) acc[j] += ts[(g * 4 + j) * FILT + k] * w;
        }
        #pragma unroll
        for (int j = 0; j < 4; ++j) {
            float o = acc[j];
            if (RESID) o += Hin[(n0 + j) * HID + c];
            Hout[(n0 + j) * HID + c] = o;
        }
        __syncthreads();
    }
}

__global__ void k_pool(const float* __restrict__ hout, const int* __restrict__ batch,
                       float* __restrict__ out) {
    int g = blockIdx.x;
    int c = threadIdx.x;
    int a = 0, b = N_NODES;
    while (a < b) { int m = (a + b) >> 1; if (batch[m] < g) a = m + 1; else b = m; }
    int lo = a;
    b = N_NODES;
    while (a < b) { int m = (a + b) >> 1; if (batch[m] < g + 1) a = m + 1; else b = m; }
    int hi = a;
    float s = 0.f;
    for (int n = lo; n < hi; ++n) s += hout[n * HID + c];
    int cnt = hi - lo;
    out[g * HID + c] = s / fmaxf((float)cnt, 1.0f);
}

extern "C" void kernel_launch(void* const* d_in, const int* in_sizes, int n_in,
                              void* d_out, int out_size, void* d_ws, size_t ws_size,
                              hipStream_t stream) {
    const int*   z       = (const int*)  d_in[0];
    const float* pos     = (const float*)d_in[1];
    const int*   batch   = (const int*)  d_in[2];
    const int*   ei      = (const int*)  d_in[3];
    const float* emb     = (const float*)d_in[4];
    const float* mlp1_w  = (const float*)d_in[5];
    const float* mlp1_b  = (const float*)d_in[6];
    const float* mlp2_w  = (const float*)d_in[7];
    const float* mlp2_b  = (const float*)d_in[8];
    const float* cl1_w   = (const float*)d_in[9];
    const float* cl2_w   = (const float*)d_in[10];
    const float* cl2_b   = (const float*)d_in[11];
    const float* lin_w   = (const float*)d_in[12];
    const float* lin_b   = (const float*)d_in[13];
    const float* out1_w  = (const float*)d_in[14];
    const float* out1_b  = (const float*)d_in[15];
    const float* out2_w  = (const float*)d_in[16];
    const float* out2_b  = (const float*)d_in[17];

    float* ws     = (float*)d_ws;
    float* h      = ws;                              // 2M floats
    float* xh     = h    + (size_t)N_NODES * HID;    // 2M
    float* agg    = xh   + (size_t)N_NODES * HID;    // 2M
    float* ewp    = agg  + (size_t)N_NODES * HID;    // 512K
    int*   colp   = (int*)(ewp + N_EDGES);           // 512K
    int*   rowp   = colp + N_EDGES;                  // 512K
    int*   cnt    = rowp + N_EDGES;                  // 16K
    int*   rowptr = cnt + N_NODES;                   // 16K+1
    int*   wo     = rowptr + N_NODES + 1;            // 16K
    float* ftab   = (float*)(wo + N_NODES);          // NL*TROWS*FILT = 1.57M

    hipMemsetAsync(cnt, 0, N_NODES * sizeof(int), stream);
    k_embed<<<N_NODES * HID / 256, 256, 0, stream>>>(z, emb, h);
    k_hist<<<N_EDGES / 256, 256, 0, stream>>>(ei, cnt);
    k_scan<<<1, 1024, 0, stream>>>(cnt, rowptr, wo);
    k_scatter<<<N_EDGES / 256, 256, 0, stream>>>(ei, pos, wo, colp, rowp, ewp);
    k_tab<<<NL * 32, 512, 0, stream>>>(mlp1_w, mlp1_b, mlp2_w, mlp2_b, ftab);

    for (int i = 0; i < NL; ++i) {
        k_xh<<<256, 1024, 0, stream>>>(h, cl1_w + (size_t)i * HID * FILT, xh);
        k_edge2<<<N_NODES / RPB, 512, 0, stream>>>(
            ewp, colp, rowp, rowptr, xh,
            ftab + (size_t)i * TROWS * FILT, agg);
        k_node<true><<<256, 1024, 0, stream>>>(agg,
                                               cl2_w + (size_t)i * FILT * HID,
                                               cl2_b + (size_t)i * HID,
                                               lin_w + (size_t)i * HID * HID,
                                               lin_b + (size_t)i * HID,
                                               h, h);
    }
    k_node<false><<<256, 1024, 0, stream>>>(h, out1_w, out1_b, out2_w, out2_b,
                                            nullptr, xh);
    k_pool<<<N_GRAPHS, HID, 0, stream>>>(xh, batch, (float*)d_out);
}